// Round 5
// baseline (401.408 us; speedup 1.0000x reference)
//
#include <hip/hip_runtime.h>

#define BB 32
#define HH 384
#define WW 1280
#define KS 9
#define NL 64     // lanes per wave
// lane l holds h = 6l..6l+5 as three packed float2 register pairs

typedef float f2v __attribute__((ext_vector_type(2)));
typedef float4 f4;

// DPP wave shifts: neighbor-lane exchange at VALU latency; bound_ctrl=true
// zero-fills the edge lane (free zero padding). Verified rounds 2-4.
__device__ __forceinline__ float dpp_up1(float v) {   // lane i <- lane i-1; lane 0 <- 0
    return __int_as_float(__builtin_amdgcn_mov_dpp(__float_as_int(v), 0x138, 0xf, 0xf, true));
}
__device__ __forceinline__ float dpp_dn1(float v) {   // lane i <- lane i+1; lane 63 <- 0
    return __int_as_float(__builtin_amdgcn_mov_dpp(__float_as_int(v), 0x130, 0xf, 0xf, true));
}
__device__ __forceinline__ float comp4(const f4& q, int u) {
    return (u == 0) ? q.x : (u == 1) ? q.y : (u == 2) ? q.z : q.w;
}
__device__ __forceinline__ void set4(f4& q, int u, float val) {
    if (u == 0) q.x = val; else if (u == 1) q.y = val;
    else if (u == 2) q.z = val; else q.w = val;
}

// 9-tap correlation + ReLU, shuffle-free split:
//   even taps -> v_pk_fma_f32 on aligned pairs P[p..p+4]
//   odd  taps -> scalar v_fmac_f32 on pair HALVES (no Q pairs, no movs)
// n[t] = padded p[6l-4+t]; P[m] = (n[2m], n[2m+1]):
//   P0=(up v2, up v3)  P1=(up v4, up v5)  P2=V0  P3=V1  P4=V2
//   P5=(dn v0, dn v1)  P6=(dn v2, dn v3)
// out j=2p   : even k -> P[p+k/2].x ; odd k -> P[p+(k-1)/2].y
// out j=2p+1 : even k -> P[p+k/2].y ; odd k -> P[p+(k+1)/2].x
__device__ __forceinline__ void conv9h(const f2v (&V)[3], const f2v (&Wp)[KS],
                                       const float (&w)[KS], f2v (&A)[3]) {
    f2v P0, P1, P5, P6;
    P0.x = dpp_up1(V[1].x); P0.y = dpp_up1(V[1].y);
    P1.x = dpp_up1(V[2].x); P1.y = dpp_up1(V[2].y);
    P5.x = dpp_dn1(V[0].x); P5.y = dpp_dn1(V[0].y);
    P6.x = dpp_dn1(V[1].x); P6.y = dpp_dn1(V[1].y);
    const f2v P[7] = {P0, P1, V[0], V[1], V[2], P5, P6};
#pragma unroll
    for (int p = 0; p < 3; ++p) {
        f2v a = Wp[0] * P[p];
        a = __builtin_elementwise_fma(Wp[2], P[p + 1], a);
        a = __builtin_elementwise_fma(Wp[4], P[p + 2], a);
        a = __builtin_elementwise_fma(Wp[6], P[p + 3], a);
        a = __builtin_elementwise_fma(Wp[8], P[p + 4], a);
        float ax = a.x, ay = a.y;
        ax = fmaf(w[1], P[p].y,     ax);
        ax = fmaf(w[3], P[p + 1].y, ax);
        ax = fmaf(w[5], P[p + 2].y, ax);
        ax = fmaf(w[7], P[p + 3].y, ax);
        ay = fmaf(w[1], P[p + 1].x, ay);
        ay = fmaf(w[3], P[p + 2].x, ay);
        ay = fmaf(w[5], P[p + 3].x, ay);
        ay = fmaf(w[7], P[p + 4].x, ay);
        A[p].x = fmaxf(ax, 0.f);
        A[p].y = fmaxf(ay, 0.f);
    }
}

// x loads: 4 columns, one aligned float4 per h-row
__device__ __forceinline__ void ldx(const float* __restrict__ xb, int h0, int col,
                                    f4 (&X)[6]) {
#pragma unroll
    for (int j = 0; j < 6; ++j)
        X[j] = *(const f4*)(xb + (size_t)(h0 + j) * WW + col);
}

// ws layout per batch (interleaved): column w at wsb + w*192, pair p at
// [p*64 + lane] -> uniform base, fixed voffset l*8, imm offsets 512/1024.
template<bool FIRST>
__device__ __forceinline__ void p1g(f2v (&V)[3], const f4 (&X)[6],
                                    const f2v (&Wp)[KS], const float (&w)[KS],
                                    f2v* __restrict__ wsb, int l, int w0) {
#pragma unroll
    for (int u = 0; u < 4; ++u) {
        if (FIRST && u == 0) {
            V[0].x = X[0].x; V[0].y = X[1].x;
            V[1].x = X[2].x; V[1].y = X[3].x;
            V[2].x = X[4].x; V[2].y = X[5].x;
        } else {
            f2v A[3];
            conv9h(V, Wp, w, A);
            V[0].x = comp4(X[0], u) + A[0].x;  V[0].y = comp4(X[1], u) + A[0].y;
            V[1].x = comp4(X[2], u) + A[1].x;  V[1].y = comp4(X[3], u) + A[1].y;
            V[2].x = comp4(X[4], u) + A[2].x;  V[2].y = comp4(X[5], u) + A[2].y;
        }
        f2v* c = wsb + (size_t)(w0 + u) * 192;
        c[l] = V[0]; c[l + 64] = V[1]; c[l + 128] = V[2];
    }
}

__device__ __forceinline__ void ldo(const f2v* __restrict__ wsb, int l, int w0,
                                    f2v (&OG)[4][3]) {
#pragma unroll
    for (int u = 0; u < 4; ++u) {
        const f2v* c = wsb + (size_t)(w0 + u) * 192;
        OG[u][0] = c[l]; OG[u][1] = c[l + 64]; OG[u][2] = c[l + 128];
    }
}

// pass-2 step x4 descending into the 8-column register output window
template<bool FIRST>
__device__ __forceinline__ void p2g(f2v (&V)[3], const f2v (&OG)[4][3], int cbase,
                                    f4 (&ob)[6][2], const f2v (&Wp)[KS],
                                    const float (&w)[KS]) {
#pragma unroll
    for (int uu = 0; uu < 4; ++uu) {
        const int u = 3 - uu;
        if (FIRST && u == 3) {
            V[0] = OG[3][0]; V[1] = OG[3][1]; V[2] = OG[3][2];
        } else {
            f2v A[3];
            conv9h(V, Wp, w, A);
            V[0] = OG[u][0] + A[0];     // v_pk_add_f32
            V[1] = OG[u][1] + A[1];
            V[2] = OG[u][2] + A[2];
        }
        const int c = cbase + u;
        set4(ob[0][c >> 2], c & 3, V[0].x);
        set4(ob[1][c >> 2], c & 3, V[0].y);
        set4(ob[2][c >> 2], c & 3, V[1].x);
        set4(ob[3][c >> 2], c & 3, V[1].y);
        set4(ob[4][c >> 2], c & 3, V[2].x);
        set4(ob[5][c >> 2], c & 3, V[2].y);
    }
}

// flush 8 buffered columns as two float4 row segments per h-row
__device__ __forceinline__ void flush8(const f4 (&ob)[6][2], float* __restrict__ outb,
                                       int h0, int w8) {
#pragma unroll
    for (int j = 0; j < 6; ++j) {
        *(f4*)(outb + (size_t)(h0 + j) * WW + w8)     = ob[j][0];
        *(f4*)(outb + (size_t)(h0 + j) * WW + w8 + 4) = ob[j][1];
    }
}

__global__ __launch_bounds__(NL, 1) void scnn_scan(const float* __restrict__ x,
                                                   float* __restrict__ ws,
                                                   float* __restrict__ out,
                                                   const float* __restrict__ w_lr,
                                                   const float* __restrict__ w_rl) {
    const int b  = blockIdx.x;
    const int l  = threadIdx.x;
    const int h0 = l * 6;

    const float* xb   = x   + (size_t)b * HH * WW;
    float*       outb = out + (size_t)b * HH * WW;
    f2v*         wsb  = (f2v*)ws + (size_t)b * WW * 192;

    float wl[KS], wr[KS];
    f2v Wlp[KS], Wrp[KS];
#pragma unroll
    for (int k = 0; k < KS; ++k) {
        wl[k] = w_lr[k]; wr[k] = w_rl[k];
        f2v ta, tc;
        ta.x = wl[k]; ta.y = wl[k];  tc.x = wr[k]; tc.y = wr[k];
        Wlp[k] = ta; Wrp[k] = tc;
    }

    f2v V[3];

    // ================= pass 1 (left -> right) =================
    {
        f4 XA[6], XB[6], XC[6], XD[6];
        ldx(xb, h0, 0, XA); ldx(xb, h0, 4, XB); ldx(xb, h0, 8, XC); ldx(xb, h0, 12, XD);
        // macro-iter 0 peeled (col 0 special)
        p1g<true >(V, XA, Wlp, wl, wsb, l, 0);  ldx(xb, h0, 16, XA);
        p1g<false>(V, XB, Wlp, wl, wsb, l, 4);  ldx(xb, h0, 20, XB);
        p1g<false>(V, XC, Wlp, wl, wsb, l, 8);  ldx(xb, h0, 24, XC);
        p1g<false>(V, XD, Wlp, wl, wsb, l, 12); ldx(xb, h0, 28, XD);
#pragma unroll 1
        for (int m = 1; m < 79; ++m) {
            const int c0 = 16 * m;
            p1g<false>(V, XA, Wlp, wl, wsb, l, c0 + 0);  ldx(xb, h0, c0 + 16, XA);
            p1g<false>(V, XB, Wlp, wl, wsb, l, c0 + 4);  ldx(xb, h0, c0 + 20, XB);
            p1g<false>(V, XC, Wlp, wl, wsb, l, c0 + 8);  ldx(xb, h0, c0 + 24, XC);
            p1g<false>(V, XD, Wlp, wl, wsb, l, c0 + 12); ldx(xb, h0, c0 + 28, XD);
        }
        // epilogue: cols 1264..1279, no prefetch
        p1g<false>(V, XA, Wlp, wl, wsb, l, 1264);
        p1g<false>(V, XB, Wlp, wl, wsb, l, 1268);
        p1g<false>(V, XC, Wlp, wl, wsb, l, 1272);
        p1g<false>(V, XD, Wlp, wl, wsb, l, 1276);
    }

    // pass-1 ws stores must be retired before pass-2 reads them back
    asm volatile("s_waitcnt vmcnt(0)" ::: "memory");

    // ================= pass 2 (right -> left) =================
    {
        f2v GA[4][3], GB[4][3], GC[4][3], GD[4][3];
        ldo(wsb, l, 1276, GA);
        ldo(wsb, l, 1272, GB);
        ldo(wsb, l, 1268, GC);
        ldo(wsb, l, 1264, GD);
        f4 ob[6][2];
        // macro-iter 0 peeled (col 1279 special)
        p2g<true >(V, GA, 4, ob, Wrp, wr); ldo(wsb, l, 1260, GA);
        p2g<false>(V, GB, 0, ob, Wrp, wr); ldo(wsb, l, 1256, GB);
        flush8(ob, outb, h0, 1272);
        p2g<false>(V, GC, 4, ob, Wrp, wr); ldo(wsb, l, 1252, GC);
        p2g<false>(V, GD, 0, ob, Wrp, wr); ldo(wsb, l, 1248, GD);
        flush8(ob, outb, h0, 1264);
#pragma unroll 1
        for (int t = 1; t < 79; ++t) {
            const int cA = 1276 - 16 * t;    // column base of buffer A this iter
            p2g<false>(V, GA, 4, ob, Wrp, wr); ldo(wsb, l, cA - 16, GA);
            p2g<false>(V, GB, 0, ob, Wrp, wr); ldo(wsb, l, cA - 20, GB);
            flush8(ob, outb, h0, cA - 4);
            p2g<false>(V, GC, 4, ob, Wrp, wr); ldo(wsb, l, cA - 24, GC);
            p2g<false>(V, GD, 0, ob, Wrp, wr); ldo(wsb, l, cA - 28, GD);
            flush8(ob, outb, h0, cA - 12);
        }
        // epilogue: cols 15..0, no prefetch
        p2g<false>(V, GA, 4, ob, Wrp, wr);
        p2g<false>(V, GB, 0, ob, Wrp, wr);
        flush8(ob, outb, h0, 8);
        p2g<false>(V, GC, 4, ob, Wrp, wr);
        p2g<false>(V, GD, 0, ob, Wrp, wr);
        flush8(ob, outb, h0, 0);
    }
}

extern "C" void kernel_launch(void* const* d_in, const int* in_sizes, int n_in,
                              void* d_out, int out_size, void* d_ws, size_t ws_size,
                              hipStream_t stream) {
    const float* x    = (const float*)d_in[0];
    const float* w_lr = (const float*)d_in[1];
    const float* w_rl = (const float*)d_in[2];
    float* out = (float*)d_out;
    float* ws  = (float*)d_ws;   // 32 batches * 1280 cols * 192 f2v = 60 MB

    scnn_scan<<<BB, NL, 0, stream>>>(x, ws, out, w_lr, w_rl);
}

// Round 6
// 343.306 us; speedup vs baseline: 1.1692x; 1.1692x over previous
//
#include <hip/hip_runtime.h>

#define BB 32
#define HH 384
#define WW 1280
#define KS 9
#define NL 64
#define NP 640                 // column pairs per batch
#define BSTRIDE (NP * 192)     // f4v elements per batch plane

typedef float f2v __attribute__((ext_vector_type(2)));
typedef float f4v __attribute__((ext_vector_type(4)));

// DPP wave shifts: neighbor-lane exchange; bound_ctrl=true zero-fills the edge
// lane (free zero padding for the H-conv). Verified rounds 2-5.
__device__ __forceinline__ float dpp_up1(float v) {   // lane i <- i-1; lane 0 <- 0
    return __int_as_float(__builtin_amdgcn_mov_dpp(__float_as_int(v), 0x138, 0xf, 0xf, true));
}
__device__ __forceinline__ float dpp_dn1(float v) {   // lane i <- i+1; lane 63 <- 0
    return __int_as_float(__builtin_amdgcn_mov_dpp(__float_as_int(v), 0x130, 0xf, 0xf, true));
}
__device__ __forceinline__ void set4(f4v& q, int u, float val) {
    if (u == 0) q.x = val; else if (u == 1) q.y = val;
    else if (u == 2) q.z = val; else q.w = val;
}

// ---------------------------------------------------------------------------
// Pre-transpose: x[b][h][w] -> xp[b][q][p][lane] f4v where
//   f4v = { x[6l+2p][2q], x[6l+2p+1][2q], x[6l+2p][2q+1], x[6l+2p+1][2q+1] }
// (.xy = even column pair, .zw = odd column pair). Bulk parallel, both sides
// coalesced via an LDS tile.
// ---------------------------------------------------------------------------
__global__ __launch_bounds__(512) void scnn_tr(const float* __restrict__ x,
                                               f4v* __restrict__ xp) {
    __shared__ float tile[HH][33];
    const int b  = blockIdx.y;
    const int c0 = blockIdx.x * 32;
    const int t  = threadIdx.x;       // 0..511
    const int col = t & 31;
    const int r0  = t >> 5;           // 0..15
    const float* xb = x + (size_t)b * HH * WW + c0;
#pragma unroll
    for (int k = 0; k < 24; ++k) {
        const int r = r0 + 16 * k;
        tile[r][col] = xb[(size_t)r * WW + col];
    }
    __syncthreads();
    f4v* xpb = xp + (size_t)b * BSTRIDE + (size_t)(c0 >> 1) * 192;
#pragma unroll
    for (int i = 0; i < 6; ++i) {
        const int idx = i * 512 + t;          // qq*192 + p*64 + l
        const int qq  = idx / 192;
        const int rem = idx - qq * 192;
        const int p   = rem >> 6;
        const int l   = rem & 63;
        const int h   = 6 * l + 2 * p;
        const int cc  = 2 * qq;
        f4v v;
        v.x = tile[h][cc];     v.y = tile[h + 1][cc];
        v.z = tile[h][cc + 1]; v.w = tile[h + 1][cc + 1];
        xpb[idx] = v;
    }
}

// ---------------------------------------------------------------------------
// 9-tap correlation + ReLU on one register column held in halves of VV[3].
// ZW=true reads the .zw halves (odd column), else .xy (even). Even taps via
// aligned pairs, odd taps via scalar fma on pair halves (round-5 verified).
// ---------------------------------------------------------------------------
template<bool ZW>
__device__ __forceinline__ void conv9(const f4v (&VV)[3], const f2v (&Wp)[KS],
                                      const float (&w)[KS], f2v (&A)[3]) {
    f2v V0, V1, V2;
    if constexpr (ZW) { V0 = VV[0].zw; V1 = VV[1].zw; V2 = VV[2].zw; }
    else              { V0 = VV[0].xy; V1 = VV[1].xy; V2 = VV[2].xy; }
    f2v P0, P1, P5, P6;
    P0.x = dpp_up1(V1.x); P0.y = dpp_up1(V1.y);
    P1.x = dpp_up1(V2.x); P1.y = dpp_up1(V2.y);
    P5.x = dpp_dn1(V0.x); P5.y = dpp_dn1(V0.y);
    P6.x = dpp_dn1(V1.x); P6.y = dpp_dn1(V1.y);
    const f2v P[7] = {P0, P1, V0, V1, V2, P5, P6};
#pragma unroll
    for (int p = 0; p < 3; ++p) {
        f2v a = Wp[0] * P[p];
        a = __builtin_elementwise_fma(Wp[2], P[p + 1], a);
        a = __builtin_elementwise_fma(Wp[4], P[p + 2], a);
        a = __builtin_elementwise_fma(Wp[6], P[p + 3], a);
        a = __builtin_elementwise_fma(Wp[8], P[p + 4], a);
        float ax = a.x, ay = a.y;
        ax = fmaf(w[1], P[p].y,     ax);
        ax = fmaf(w[3], P[p + 1].y, ax);
        ax = fmaf(w[5], P[p + 2].y, ax);
        ax = fmaf(w[7], P[p + 3].y, ax);
        ay = fmaf(w[1], P[p + 1].x, ay);
        ay = fmaf(w[3], P[p + 2].x, ay);
        ay = fmaf(w[5], P[p + 3].x, ay);
        ay = fmaf(w[7], P[p + 4].x, ay);
        A[p].x = fmaxf(ax, 0.f);
        A[p].y = fmaxf(ay, 0.f);
    }
}

// load one GROUP = 2 column pairs = 6 coalesced f4v
__device__ __forceinline__ void ldxp(const f4v* __restrict__ wsb, int l, int pq,
                                     f4v (&X)[2][3]) {
    const f4v* c = wsb + (size_t)pq * 192 + l;
    X[0][0] = c[0];   X[0][1] = c[64];  X[0][2] = c[128];
    X[1][0] = c[192]; X[1][1] = c[256]; X[1][2] = c[320];
}

// pass-1, one pair: even col then odd col, store pair (in place over xp)
template<bool FIRST>
__device__ __forceinline__ void p1pair(f4v (&VV)[3], const f4v (&XP)[3],
                                       const f2v (&Wp)[KS], const float (&w)[KS],
                                       f4v* __restrict__ cbase, int l) {
    if (FIRST) {
        VV[0].xy = XP[0].xy; VV[1].xy = XP[1].xy; VV[2].xy = XP[2].xy;
    } else {
        f2v A[3];
        conv9<true>(VV, Wp, w, A);          // reads prev odd col (.zw)
        VV[0].xy = XP[0].xy + A[0];
        VV[1].xy = XP[1].xy + A[1];
        VV[2].xy = XP[2].xy + A[2];
    }
    {
        f2v A[3];
        conv9<false>(VV, Wp, w, A);         // reads even col (.xy)
        VV[0].zw = XP[0].zw + A[0];
        VV[1].zw = XP[1].zw + A[1];
        VV[2].zw = XP[2].zw + A[2];
    }
    cbase[l] = VV[0]; cbase[l + 64] = VV[1]; cbase[l + 128] = VV[2];
}

template<bool FIRST>
__device__ __forceinline__ void p1grp(f4v (&VV)[3], const f4v (&X)[2][3],
                                      f4v* __restrict__ wsb, int pq, int l,
                                      const f2v (&Wp)[KS], const float (&w)[KS]) {
    p1pair<FIRST>(VV, X[0], Wp, w, wsb + (size_t)pq * 192, l);
    p1pair<false>(VV, X[1], Wp, w, wsb + (size_t)(pq + 1) * 192, l);
}

// pass-2, one pair DESCENDING: odd col (chi) then even col (chi-1), into the
// 8-column register output window ob.
template<bool FIRST>
__device__ __forceinline__ void p2pair(f4v (&VV)[3], const f4v (&OG)[3],
                                       f4v (&ob)[6][2], int chi,
                                       const f2v (&Wp)[KS], const float (&w)[KS]) {
    if (FIRST) {
        VV[0].zw = OG[0].zw; VV[1].zw = OG[1].zw; VV[2].zw = OG[2].zw;
    } else {
        f2v A[3];
        conv9<false>(VV, Wp, w, A);         // reads col+1 (even, .xy)
        VV[0].zw = OG[0].zw + A[0];
        VV[1].zw = OG[1].zw + A[1];
        VV[2].zw = OG[2].zw + A[2];
    }
    set4(ob[0][chi >> 2], chi & 3, VV[0].z);
    set4(ob[1][chi >> 2], chi & 3, VV[0].w);
    set4(ob[2][chi >> 2], chi & 3, VV[1].z);
    set4(ob[3][chi >> 2], chi & 3, VV[1].w);
    set4(ob[4][chi >> 2], chi & 3, VV[2].z);
    set4(ob[5][chi >> 2], chi & 3, VV[2].w);
    {
        f2v A[3];
        conv9<true>(VV, Wp, w, A);          // reads col+1 (odd, .zw)
        VV[0].xy = OG[0].xy + A[0];
        VV[1].xy = OG[1].xy + A[1];
        VV[2].xy = OG[2].xy + A[2];
    }
    const int clo = chi - 1;
    set4(ob[0][clo >> 2], clo & 3, VV[0].x);
    set4(ob[1][clo >> 2], clo & 3, VV[0].y);
    set4(ob[2][clo >> 2], clo & 3, VV[1].x);
    set4(ob[3][clo >> 2], clo & 3, VV[1].y);
    set4(ob[4][clo >> 2], clo & 3, VV[2].x);
    set4(ob[5][clo >> 2], clo & 3, VV[2].y);
}

template<bool FIRST>
__device__ __forceinline__ void p2grp(f4v (&VV)[3], const f4v (&G)[2][3],
                                      f4v (&ob)[6][2], int cbase,
                                      const f2v (&Wp)[KS], const float (&w)[KS]) {
    p2pair<FIRST>(VV, G[1], ob, cbase + 3, Wp, w);
    p2pair<false>(VV, G[0], ob, cbase + 1, Wp, w);
}

// flush 8 buffered columns as two f4v row segments per h-row
__device__ __forceinline__ void flush8(const f4v (&ob)[6][2], float* __restrict__ outb,
                                       int h0, int w8) {
#pragma unroll
    for (int j = 0; j < 6; ++j) {
        *(f4v*)(outb + (size_t)(h0 + j) * WW + w8)     = ob[j][0];
        *(f4v*)(outb + (size_t)(h0 + j) * WW + w8 + 4) = ob[j][1];
    }
}

__global__ __launch_bounds__(NL, 1) void scnn_scan(f4v* __restrict__ xp,
                                                   float* __restrict__ out,
                                                   const float* __restrict__ w_lr,
                                                   const float* __restrict__ w_rl) {
    const int b  = blockIdx.x;
    const int l  = threadIdx.x;
    const int h0 = l * 6;

    f4v*   wsb  = xp  + (size_t)b * BSTRIDE;    // xp overwritten in place by out1
    float* outb = out + (size_t)b * HH * WW;

    float wl[KS], wr[KS];
    f2v Wlp[KS], Wrp[KS];
#pragma unroll
    for (int k = 0; k < KS; ++k) {
        wl[k] = w_lr[k]; wr[k] = w_rl[k];
        f2v ta, tc;
        ta.x = wl[k]; ta.y = wl[k];  tc.x = wr[k]; tc.y = wr[k];
        Wlp[k] = ta; Wrp[k] = tc;
    }

    f4v VV[3];

    // ================= pass 1 (left -> right) =================
    {
        f4v XA[2][3], XB[2][3], XC[2][3], XD[2][3];
        ldxp(wsb, l, 0, XA); ldxp(wsb, l, 2, XB); ldxp(wsb, l, 4, XC); ldxp(wsb, l, 6, XD);
        p1grp<true >(VV, XA, wsb, 0, l, Wlp, wl); ldxp(wsb, l, 8,  XA);
        p1grp<false>(VV, XB, wsb, 2, l, Wlp, wl); ldxp(wsb, l, 10, XB);
        p1grp<false>(VV, XC, wsb, 4, l, Wlp, wl); ldxp(wsb, l, 12, XC);
        p1grp<false>(VV, XD, wsb, 6, l, Wlp, wl); ldxp(wsb, l, 14, XD);
#pragma unroll 1
        for (int m = 1; m < 79; ++m) {
            const int pq0 = 8 * m;
            p1grp<false>(VV, XA, wsb, pq0 + 0, l, Wlp, wl); ldxp(wsb, l, pq0 + 8,  XA);
            p1grp<false>(VV, XB, wsb, pq0 + 2, l, Wlp, wl); ldxp(wsb, l, pq0 + 10, XB);
            p1grp<false>(VV, XC, wsb, pq0 + 4, l, Wlp, wl); ldxp(wsb, l, pq0 + 12, XC);
            p1grp<false>(VV, XD, wsb, pq0 + 6, l, Wlp, wl); ldxp(wsb, l, pq0 + 14, XD);
        }
        p1grp<false>(VV, XA, wsb, 632, l, Wlp, wl);
        p1grp<false>(VV, XB, wsb, 634, l, Wlp, wl);
        p1grp<false>(VV, XC, wsb, 636, l, Wlp, wl);
        p1grp<false>(VV, XD, wsb, 638, l, Wlp, wl);
    }

    // out1 stores must be retired before pass-2 reads them back
    asm volatile("s_waitcnt vmcnt(0)" ::: "memory");

    // ================= pass 2 (right -> left) =================
    {
        f4v GA[2][3], GB[2][3], GC[2][3], GD[2][3];
        ldxp(wsb, l, 638, GA); ldxp(wsb, l, 636, GB);
        ldxp(wsb, l, 634, GC); ldxp(wsb, l, 632, GD);
        f4v ob[6][2];
        p2grp<true >(VV, GA, ob, 4, Wrp, wr); ldxp(wsb, l, 630, GA);
        p2grp<false>(VV, GB, ob, 0, Wrp, wr); ldxp(wsb, l, 628, GB);
        flush8(ob, outb, h0, 1272);
        p2grp<false>(VV, GC, ob, 4, Wrp, wr); ldxp(wsb, l, 626, GC);
        p2grp<false>(VV, GD, ob, 0, Wrp, wr); ldxp(wsb, l, 624, GD);
        flush8(ob, outb, h0, 1264);
#pragma unroll 1
        for (int t2 = 1; t2 < 79; ++t2) {
            const int pqA = 638 - 8 * t2;
            p2grp<false>(VV, GA, ob, 4, Wrp, wr); ldxp(wsb, l, pqA - 8,  GA);
            p2grp<false>(VV, GB, ob, 0, Wrp, wr); ldxp(wsb, l, pqA - 10, GB);
            flush8(ob, outb, h0, 2 * pqA - 4);
            p2grp<false>(VV, GC, ob, 4, Wrp, wr); ldxp(wsb, l, pqA - 12, GC);
            p2grp<false>(VV, GD, ob, 0, Wrp, wr); ldxp(wsb, l, pqA - 14, GD);
            flush8(ob, outb, h0, 2 * pqA - 12);
        }
        p2grp<false>(VV, GA, ob, 4, Wrp, wr);
        p2grp<false>(VV, GB, ob, 0, Wrp, wr);
        flush8(ob, outb, h0, 8);
        p2grp<false>(VV, GC, ob, 4, Wrp, wr);
        p2grp<false>(VV, GD, ob, 0, Wrp, wr);
        flush8(ob, outb, h0, 0);
    }
}

extern "C" void kernel_launch(void* const* d_in, const int* in_sizes, int n_in,
                              void* d_out, int out_size, void* d_ws, size_t ws_size,
                              hipStream_t stream) {
    const float* x    = (const float*)d_in[0];
    const float* w_lr = (const float*)d_in[1];
    const float* w_rl = (const float*)d_in[2];
    float* out = (float*)d_out;
    f4v*   xp  = (f4v*)d_ws;    // 32 * 640 * 192 f4v = 62.9 MB (reused in place)

    scnn_tr<<<dim3(WW / 32, BB), 512, 0, stream>>>(x, xp);
    scnn_scan<<<BB, NL, 0, stream>>>(xp, out, w_lr, w_rl);
}